// Round 10
// baseline (1106.825 us; speedup 1.0000x reference)
//
#include <hip/hip_runtime.h>
#include <hip/hip_fp16.h>
#include <hip/hip_bf16.h>
#include <hip/hip_cooperative_groups.h>

namespace cg = cooperative_groups;

// SlotAttention restructured:
//  dots = qs . x   with qs = LN(slots) @ (scale * Wq^T Wk)   (K never materialized)
//  updates folded:  gates_ih = (agg*fac) @ (Wih@Wv)^T        (V and upd never materialized)
// x = LN(inputs) fp16. fp32 accumulation. Output fp32.
// R9: every tail decomposition costs ~95us/iter vs ~8us of math => dispatch/drain
// overhead dominates. R10: ONE cooperative kernel for the whole iteration loop
// (grid.sync between phases). Att phase2 channel-per-lane (no 32KB aggl -> 4
// blocks/CU). Tail: one block per slot-row, GRU in registers, half2-K weights.

#define BB 64
#define NN 4096
#define DD 256
#define NSL 8
#define NITER 3

__device__ __forceinline__ float wredsum(float v){
#pragma unroll
  for(int m=32;m;m>>=1) v += __shfl_xor(v, m, 64);
  return v;
}
__device__ __forceinline__ float2 u2f2(unsigned u){ __half2 h; __builtin_memcpy(&h,&u,4); return __half22float2(h); }
__device__ __forceinline__ float sigm(float v){ return 1.0f/(1.0f+__expf(-v)); }

// ---------------- prep: packed half2-over-K weights + slots broadcast ----------------
// Wgp halves idx: (( (g*128 + (k>>1))*256 + c )*2 + (k&1)), g=0..5 (0..2 ih=WC, 3..5 hh)
__global__ __launch_bounds__(256) void k_prep(
    const float* __restrict__ Whh, const float* __restrict__ W1,
    const float* __restrict__ W2,  const float* __restrict__ sinit,
    __half* __restrict__ Wgp, __half* __restrict__ W1p, __half* __restrict__ W2p,
    float* __restrict__ slots){
  for(int idx=blockIdx.x*256+threadIdx.x; idx<851968; idx+=gridDim.x*256){
    if(idx<196608){
      int col=idx>>8, k=idx&255; int g=3+(col>>8), c=col&255;
      Wgp[(((size_t)g*128+(k>>1))*256+c)*2+(k&1)] = __float2half(Whh[idx]);
    } else if(idx<458752){
      int k2=idx-196608; int col=k2>>8, k=k2&255; int g=col>>8, c=col&255;
      W1p[(((size_t)g*128+(k>>1))*256+c)*2+(k&1)] = __float2half(W1[k2]);
    } else if(idx<720896){
      int k3=idx-458752; int col=k3>>10, k=k3&1023;
      W2p[(((size_t)(k>>1))*256+col)*2+(k&1)] = __float2half(W2[k3]);
    } else {
      int k4=idx-720896; slots[k4]=sinit[k4&2047];
    }
  }
}

// ---------------- WC = Wih @ Wv -> Wgp g=0..2 ----------------
__global__ __launch_bounds__(256) void k_WC(const float* __restrict__ Wih, const float* __restrict__ Wv,
                                            __half* __restrict__ Wgp){
  int col=blockIdx.x;  // 0..767
  int t=threadIdx.x;   // output k 0..255
  __shared__ float wr[256];
  wr[t]=Wih[col*256+t];
  __syncthreads();
  float acc=0.f;
#pragma unroll 8
  for(int d=0;d<256;d++) acc += wr[d]*Wv[d*256+t];
  int g=col>>8, c=col&255;
  Wgp[(((size_t)g*128+(t>>1))*256+c)*2+(t&1)] = __float2half(acc);
}

// ---------------- Mp[k2][c] packs M[e][c]=scale*(Wq^T Wk)[e][c] over e-pairs ----------------
__global__ __launch_bounds__(256) void k_M(const float* __restrict__ Wq, const float* __restrict__ Wk,
                                           __half* __restrict__ Mp){
  int c = blockIdx.x, e = threadIdx.x;
  float acc = 0.f;
#pragma unroll 8
  for(int d=0; d<256; d++) acc += Wq[d*256+e]*Wk[d*256+c];
  Mp[(((size_t)(e>>1))*256+c)*2+(e&1)] = __float2half(acc * 0.0625f);
}

// ---------------- x = LN(inputs) -> fp16 ----------------
__global__ __launch_bounds__(256) void k_ln_x(const float* __restrict__ in, const float* __restrict__ g,
                                              const float* __restrict__ bbv, __half* __restrict__ x){
  int row  = blockIdx.x*4 + (threadIdx.x>>6);
  int lane = threadIdx.x&63;
  const float4 v = ((const float4*)(in + (size_t)row*DD))[lane];
  float s  = v.x+v.y+v.z+v.w;
  float ss = v.x*v.x+v.y*v.y+v.z*v.z+v.w*v.w;
  s = wredsum(s); ss = wredsum(ss);
  float m = s*(1.0f/256.0f);
  float r = rsqrtf(ss*(1.0f/256.0f) - m*m + 1e-5f);
  float4 gv = ((const float4*)g)[lane];
  float4 bv = ((const float4*)bbv)[lane];
  float y0=(v.x-m)*r*gv.x+bv.x, y1=(v.y-m)*r*gv.y+bv.y;
  float y2=(v.z-m)*r*gv.z+bv.z, y3=(v.w-m)*r*gv.w+bv.w;
  __half2 h0=__floats2half2_rn(y0,y1), h1=__floats2half2_rn(y2,y3);
  uint2 u; __builtin_memcpy(&u.x,&h0,4); __builtin_memcpy(&u.y,&h1,4);
  ((uint2*)(x + (size_t)row*DD))[lane] = u;
}

// ---------------- cooperative main: [P0 qs] + 3x [P1 att | P2 tail] ----------------
__global__ __launch_bounds__(256, 4) void k_main(
    const __half* __restrict__ x, float* __restrict__ qs, float* __restrict__ slots,
    float* __restrict__ pagg,
    const __half* __restrict__ Wgp, const __half* __restrict__ W1p,
    const __half* __restrict__ W2p, const __half* __restrict__ Mp,
    const float* __restrict__ bih, const float* __restrict__ bhh,
    const float* __restrict__ lm_g, const float* __restrict__ lm_b,
    const float* __restrict__ b1, const float* __restrict__ b2,
    const float* __restrict__ ls_g, const float* __restrict__ ls_b,
    float* __restrict__ out){
  cg::grid_group grid = cg::this_grid();
  const int blk=blockIdx.x, t=threadIdx.x, G=gridDim.x;
  const int wid=t>>6, lane=t&63;
  __shared__ __align__(16) float qt[256][8];
  __shared__ __align__(16) float wl[256][8];
  __shared__ float wsl[4][8];
  __shared__ float aggS[256], slS[256], ysl[256];
  __shared__ __align__(16) float z1l[1024];
  __shared__ float redS[4], redQ[4], facS, f16S[16];
  const __half2* Wg2=(const __half2*)Wgp;
  const __half2* W12=(const __half2*)W1p;
  const __half2* W22=(const __half2*)W2p;
  const __half2* Mp2=(const __half2*)Mp;

  // ---- P0: initial qs = LN(slots) @ M
  for(int row=blk; row<512; row+=G){
    __syncthreads();
    float v = slots[(size_t)row*256+t];
    float s=wredsum(v), ss=wredsum(v*v);
    if(lane==0){ redS[wid]=s; redQ[wid]=ss; }
    __syncthreads();
    float S=redS[0]+redS[1]+redS[2]+redS[3];
    float SS=redQ[0]+redQ[1]+redQ[2]+redQ[3];
    float m=S*(1.0f/256.0f);
    float rs=rsqrtf(SS*(1.0f/256.0f)-m*m+1e-5f);
    ysl[t]=(v-m)*rs*ls_g[t]+ls_b[t];
    __syncthreads();
    float acc=0.f;
#pragma unroll 8
    for(int k2=0;k2<128;k2++){
      float2 f=__half22float2(Mp2[(size_t)k2*256+t]);
      acc += f.x*ysl[2*k2] + f.y*ysl[2*k2+1];
    }
    qs[(size_t)row*256+t]=acc;
  }
  grid.sync();

  for(int it=0; it<NITER; ++it){
    const int last = (it==NITER-1);
    // ---- P1: attention (1024 virtual blocks)
    for(int ab=blk; ab<1024; ab+=G){
      __syncthreads();
      int b = ab>>4;
      const float* qb = qs + (size_t)b*2048;
      for(int e=t;e<2048;e+=256) qt[e&255][e>>8]=qb[e];
      __syncthreads();
      size_t j = (size_t)ab*256 + t;
      const uint4* xr = (const uint4*)(x + j*DD);
      float pd[8]={0,0,0,0,0,0,0,0};
#pragma unroll 2
      for(int ch=0; ch<32; ch++){
        uint4 u = xr[ch];
        float2 f0=u2f2(u.x), f1=u2f2(u.y), f2=u2f2(u.z), f3=u2f2(u.w);
        float xv[8]={f0.x,f0.y,f1.x,f1.y,f2.x,f2.y,f3.x,f3.y};
        int c0=ch*8;
#pragma unroll
        for(int cc=0;cc<8;cc++){
          const float4* qp=(const float4*)&qt[c0+cc][0];
          float4 qa=qp[0], qc=qp[1];
          float xvv=xv[cc];
          pd[0]+=qa.x*xvv; pd[1]+=qa.y*xvv; pd[2]+=qa.z*xvv; pd[3]+=qa.w*xvv;
          pd[4]+=qc.x*xvv; pd[5]+=qc.y*xvv; pd[6]+=qc.z*xvv; pd[7]+=qc.w*xvv;
        }
      }
      float mx=pd[0];
#pragma unroll
      for(int i=1;i<8;i++) mx=fmaxf(mx,pd[i]);
      float w[8]; float ssum=0.f;
#pragma unroll
      for(int i=0;i<8;i++){ w[i]=__expf(pd[i]-mx); ssum+=w[i]; }
      float inv=1.0f/ssum;
#pragma unroll
      for(int i=0;i<8;i++){ w[i]=w[i]*inv+1e-5f; wl[t][i]=w[i]; }
      // wsum
#pragma unroll
      for(int i=0;i<8;i++){
        float s=wredsum(w[i]);
        if(lane==0) wsl[wid][i]=s;
      }
      __syncthreads();
      if(t<8) pagg[(size_t)ab*2064 + 2048 + t] = wsl[0][t]+wsl[1][t]+wsl[2][t]+wsl[3][t];
      // phase2: channel-per-lane agg
      int c = wid*64 + lane;
      float acc[8]={0,0,0,0,0,0,0,0};
      const __half* xb = x + (size_t)ab*256*DD + c;
#pragma unroll 4
      for(int j2=0;j2<256;j2++){
        float xv = __half2float(xb[(size_t)j2*DD]);
        const float4* wp=(const float4*)&wl[j2][0];
        float4 w0=wp[0], w1=wp[1];
        acc[0]+=w0.x*xv; acc[1]+=w0.y*xv; acc[2]+=w0.z*xv; acc[3]+=w0.w*xv;
        acc[4]+=w1.x*xv; acc[5]+=w1.y*xv; acc[6]+=w1.z*xv; acc[7]+=w1.w*xv;
      }
#pragma unroll
      for(int i=0;i<8;i++) pagg[(size_t)ab*2064 + i*256 + c] = acc[i];
    }
    grid.sync();
    // ---- P2: tail, one block per slot-row
    float* dst = last ? out : slots;
    for(int row=blk; row<512; row+=G){
      __syncthreads();
      int b=row>>3, i0=row&7;
      const float* pb = pagg + (size_t)b*16*2064;
      float s=0.f;
#pragma unroll
      for(int ch=0;ch<16;ch++) s += pb[ch*2064 + i0*256 + t];
      if(t<16) f16S[t]=pb[t*2064 + 2048 + i0];
      float hp = slots[(size_t)row*256+t];
      slS[t]=hp;
      __syncthreads();
      float wsum=0.f;
#pragma unroll
      for(int k2=0;k2<16;k2++) wsum+=f16S[k2];
      aggS[t]=s*(4096.0f/wsum);
      __syncthreads();
      // gates: 6 packed streams
      float a0=0,a1=0,a2=0,a3=0,a4=0,a5=0;
#pragma unroll 8
      for(int k2=0;k2<128;k2++){
        float xa0=aggS[2*k2], xa1=aggS[2*k2+1];
        float xs0=slS[2*k2],  xs1=slS[2*k2+1];
        float2 f0=__half22float2(Wg2[(size_t)(0*128+k2)*256+t]);
        float2 f1=__half22float2(Wg2[(size_t)(1*128+k2)*256+t]);
        float2 f2=__half22float2(Wg2[(size_t)(2*128+k2)*256+t]);
        float2 f3=__half22float2(Wg2[(size_t)(3*128+k2)*256+t]);
        float2 f4=__half22float2(Wg2[(size_t)(4*128+k2)*256+t]);
        float2 f5=__half22float2(Wg2[(size_t)(5*128+k2)*256+t]);
        a0+=f0.x*xa0+f0.y*xa1; a1+=f1.x*xa0+f1.y*xa1; a2+=f2.x*xa0+f2.y*xa1;
        a3+=f3.x*xs0+f3.y*xs1; a4+=f4.x*xs0+f4.y*xs1; a5+=f5.x*xs0+f5.y*xs1;
      }
      float gir=a0+bih[t], giz=a1+bih[256+t], gin=a2+bih[512+t];
      float ghr=a3+bhh[t], ghz=a4+bhh[256+t], ghn=a5+bhh[512+t];
      float rr=sigm(gir+ghr), z=sigm(giz+ghz);
      float n=tanhf(gin+rr*ghn);
      float hv=(1.0f-z)*n + z*hp;
      // MLP pre-norm
      float s1=wredsum(hv), q1=wredsum(hv*hv);
      if(lane==0){ redS[wid]=s1; redQ[wid]=q1; }
      __syncthreads();
      float S=redS[0]+redS[1]+redS[2]+redS[3];
      float SS=redQ[0]+redQ[1]+redQ[2]+redQ[3];
      float m=S*(1.0f/256.0f);
      float rs=rsqrtf(SS*(1.0f/256.0f)-m*m+1e-5f);
      ysl[t]=(hv-m)*rs*lm_g[t]+lm_b[t];
      __syncthreads();
      // mlp1: 4 packed streams
      float m0=0,m1=0,m2=0,m3=0;
#pragma unroll 8
      for(int k2=0;k2<128;k2++){
        float y0=ysl[2*k2], y1=ysl[2*k2+1];
        float2 f0=__half22float2(W12[(size_t)(0*128+k2)*256+t]);
        float2 f1=__half22float2(W12[(size_t)(1*128+k2)*256+t]);
        float2 f2=__half22float2(W12[(size_t)(2*128+k2)*256+t]);
        float2 f3=__half22float2(W12[(size_t)(3*128+k2)*256+t]);
        m0+=f0.x*y0+f0.y*y1; m1+=f1.x*y0+f1.y*y1;
        m2+=f2.x*y0+f2.y*y1; m3+=f3.x*y0+f3.y*y1;
      }
      {
        float v0=m0+b1[t];      z1l[t]      = v0>0.f?v0:0.01f*v0;
        float v1=m1+b1[256+t];  z1l[256+t]  = v1>0.f?v1:0.01f*v1;
        float v2=m2+b1[512+t];  z1l[512+t]  = v2>0.f?v2:0.01f*v2;
        float v3=m3+b1[768+t];  z1l[768+t]  = v3>0.f?v3:0.01f*v3;
      }
      __syncthreads();
      // mlp2: K=1024
      float o=0.f;
#pragma unroll 8
      for(int k2=0;k2<512;k2++){
        float2 f=__half22float2(W22[(size_t)k2*256+t]);
        o += f.x*z1l[2*k2] + f.y*z1l[2*k2+1];
      }
      float sv = hv + o + b2[t];
      dst[(size_t)row*256+t]=sv;
      if(!last){
        // slot-LN + next qs
        float s2=wredsum(sv), q2=wredsum(sv*sv);
        __syncthreads();                 // protect ysl reuse (mlp1 reads done)
        if(lane==0){ redS[wid]=s2; redQ[wid]=q2; }
        __syncthreads();
        float S2=redS[0]+redS[1]+redS[2]+redS[3];
        float SS2=redQ[0]+redQ[1]+redQ[2]+redQ[3];
        float m2_=S2*(1.0f/256.0f);
        float rs2=rsqrtf(SS2*(1.0f/256.0f)-m2_*m2_+1e-5f);
        ysl[t]=(sv-m2_)*rs2*ls_g[t]+ls_b[t];
        __syncthreads();
        float acc=0.f;
#pragma unroll 8
        for(int k2=0;k2<128;k2++){
          float2 f=__half22float2(Mp2[(size_t)k2*256+t]);
          acc += f.x*ysl[2*k2] + f.y*ysl[2*k2+1];
        }
        qs[(size_t)row*256+t]=acc;
      }
    }
    if(!last) grid.sync();
  }
}

extern "C" void kernel_launch(void* const* d_in, const int* in_sizes, int n_in,
                              void* d_out, int out_size, void* d_ws, size_t ws_size,
                              hipStream_t stream){
  const float* inputs=(const float*)d_in[0];
  const float* sinit =(const float*)d_in[1];
  const float* Wq =(const float*)d_in[2];
  const float* Wk =(const float*)d_in[3];
  const float* Wv =(const float*)d_in[4];
  const float* Wih=(const float*)d_in[5];
  const float* Whh=(const float*)d_in[6];
  const float* bih=(const float*)d_in[7];
  const float* bhh=(const float*)d_in[8];
  const float* lin_g=(const float*)d_in[9];
  const float* lin_b=(const float*)d_in[10];
  const float* ls_g=(const float*)d_in[11];
  const float* ls_b=(const float*)d_in[12];
  const float* lm_g=(const float*)d_in[13];
  const float* lm_b=(const float*)d_in[14];
  const float* W1=(const float*)d_in[15];
  const float* b1=(const float*)d_in[16];
  const float* W2=(const float*)d_in[17];
  const float* b2=(const float*)d_in[18];

  char* w=(char*)d_ws;
  __half* x    =(__half*)w; w += (size_t)BB*NN*DD*2;        // 134.2 MB
  float* qs    =(float*)w;  w += 512*256*4;
  float* slots =(float*)w;  w += 512*256*4;
  float* pagg  =(float*)w;  w += (size_t)1024*2064*4;       // 8.45 MB
  __half* Wgp  =(__half*)w; w += (size_t)6*128*256*2*2;
  __half* W1p  =(__half*)w; w += (size_t)4*128*256*2*2;
  __half* W2p  =(__half*)w; w += (size_t)512*256*2*2;
  __half* Mp   =(__half*)w; w += (size_t)128*256*2*2;

  hipLaunchKernelGGL(k_prep, dim3(1664), dim3(256), 0, stream,
                     Whh, W1, W2, sinit, Wgp, W1p, W2p, slots);
  hipLaunchKernelGGL(k_WC,   dim3(768),  dim3(256), 0, stream, Wih, Wv, Wgp);
  hipLaunchKernelGGL(k_M,    dim3(256),  dim3(256), 0, stream, Wq, Wk, Mp);
  hipLaunchKernelGGL(k_ln_x, dim3(65536),dim3(256), 0, stream, inputs, lin_g, lin_b, x);

  int nb=0;
  hipError_t e = hipOccupancyMaxActiveBlocksPerMultiprocessor(&nb, k_main, 256, 0);
  if(e!=hipSuccess || nb<1) nb=1;
  if(nb>4) nb=4;
  int gridN = nb*256; if(gridN>1024) gridN=1024;

  const __half* xc=x; const __half* Wgc=Wgp; const __half* W1c=W1p;
  const __half* W2c=W2p; const __half* Mpc=Mp;
  float* outp=(float*)d_out;
  void* args[] = {
    (void*)&xc, (void*)&qs, (void*)&slots, (void*)&pagg,
    (void*)&Wgc, (void*)&W1c, (void*)&W2c, (void*)&Mpc,
    (void*)&bih, (void*)&bhh, (void*)&lm_g, (void*)&lm_b,
    (void*)&b1, (void*)&b2, (void*)&ls_g, (void*)&ls_b, (void*)&outp
  };
  hipLaunchCooperativeKernel((void*)k_main, dim3(gridN), dim3(256), args, 0, stream);
}

// Round 11
// 403.409 us; speedup vs baseline: 2.7437x; 2.7437x over previous
//
#include <hip/hip_runtime.h>
#include <hip/hip_fp16.h>
#include <hip/hip_bf16.h>

#define BB 64
#define NN 4096
#define DD 256
#define NSL 8
#define NITER 3

__device__ __forceinline__ float wredsum(float v){
#pragma unroll
  for(int m=32;m;m>>=1) v += __shfl_xor(v, m, 64);
  return v;
}
__device__ __forceinline__ float2 u2f2(unsigned u){ __half2 h; __builtin_memcpy(&h,&u,4); return __half22float2(h); }
__device__ __forceinline__ float sigm(float v){ return 1.0f/(1.0f+__expf(-v)); }

union U4 { uint4 u; __half2 h[4]; };

__device__ __forceinline__ void st8(float* dst, uint4 uu){
  U4 v; v.u=uu;
  float2 f0=__half22float2(v.h[0]), f1=__half22float2(v.h[1]),
         f2=__half22float2(v.h[2]), f3=__half22float2(v.h[3]);
  dst[0]=f0.x; dst[1]=f0.y; dst[2]=f1.x; dst[3]=f1.y;
  dst[4]=f2.x; dst[5]=f2.y; dst[6]=f3.x; dst[7]=f3.y;
}

// ---------------- merged prep: weights + slots + WC GEMM + M GEMM + agg zero ----------------
__global__ __launch_bounds__(256) void kp_all(
    const float* __restrict__ Whh, const float* __restrict__ W1,
    const float* __restrict__ W2,  const float* __restrict__ sinit,
    const float* __restrict__ Wih, const float* __restrict__ Wv,
    const float* __restrict__ Wq,  const float* __restrict__ Wk,
    __half* __restrict__ Wg, __half* __restrict__ W1t, __half* __restrict__ W2t,
    float* __restrict__ slots, __half* __restrict__ M2h, float* __restrict__ zbuf){
  int bid=blockIdx.x, t=threadIdx.x;
  if(bid<1664){
    for(int idx=bid*256+t; idx<851968; idx+=1664*256){
      if(idx<196608){ int col=idx>>8, c=idx&255; Wg[(size_t)c*1536+768+col]=__float2half(Whh[idx]); }
      else if(idx<458752){ int k=idx-196608; int col=k>>8, c=k&255; W1t[(size_t)c*1024+col]=__float2half(W1[k]); }
      else if(idx<720896){ int k=idx-458752; int col=k>>10, c=k&1023; W2t[(size_t)c*256+col]=__float2half(W2[k]); }
      else { int k=idx-720896; slots[k]=sinit[k&2047]; }
    }
  } else if(bid<2432){
    int col=bid-1664;            // 0..767
    __shared__ float wr[256];
    wr[t]=Wih[col*256+t];
    __syncthreads();
    float acc=0.f;
#pragma unroll 8
    for(int d=0;d<256;d++) acc += wr[d]*Wv[d*256+t];
    Wg[(size_t)t*1536+col]=__float2half(acc);
  } else if(bid<2688){
    int c=bid-2432;              // 0..255
    float acc=0.f;
#pragma unroll 8
    for(int d=0;d<256;d++) acc += Wq[d*256+t]*Wk[d*256+c];
    M2h[(size_t)c*256+t]=__float2half(acc*0.0625f);
  } else {
    int idx=(bid-2688)*256+t;
    if(idx<394752) zbuf[idx]=0.f;
  }
}

// ---------------- x = LN(inputs) -> fp16 ----------------
__global__ __launch_bounds__(256) void k_ln_x(const float* __restrict__ in, const float* __restrict__ g,
                                              const float* __restrict__ bbv, __half* __restrict__ x){
  int row  = blockIdx.x*4 + (threadIdx.x>>6);
  int lane = threadIdx.x&63;
  const float4 v = ((const float4*)(in + (size_t)row*DD))[lane];
  float s  = v.x+v.y+v.z+v.w;
  float ss = v.x*v.x+v.y*v.y+v.z*v.z+v.w*v.w;
  s = wredsum(s); ss = wredsum(ss);
  float m = s*(1.0f/256.0f);
  float r = rsqrtf(ss*(1.0f/256.0f) - m*m + 1e-5f);
  float4 gv = ((const float4*)g)[lane];
  float4 bv = ((const float4*)bbv)[lane];
  float y0=(v.x-m)*r*gv.x+bv.x, y1=(v.y-m)*r*gv.y+bv.y;
  float y2=(v.z-m)*r*gv.z+bv.z, y3=(v.w-m)*r*gv.w+bv.w;
  __half2 h0=__floats2half2_rn(y0,y1), h1=__floats2half2_rn(y2,y3);
  uint2 u; __builtin_memcpy(&u.x,&h0,4); __builtin_memcpy(&u.y,&h1,4);
  ((uint2*)(x + (size_t)row*DD))[lane] = u;
}

// ---------------- initial qs = LN(slots) @ M (once); also writes slotsh ----------------
__global__ __launch_bounds__(256) void k_pre(const float* __restrict__ slots, const float* __restrict__ g,
                                             const float* __restrict__ bbv, const __half* __restrict__ M2h,
                                             float* __restrict__ qs, __half* __restrict__ slotsh){
  int row = blockIdx.x;      // 0..511
  int t = threadIdx.x;
  __shared__ __align__(16) float sn[256];
  __shared__ float red[8];
  float v = slots[row*256 + t];
  slotsh[(size_t)row*256+t]=__float2half(v);
  float s = wredsum(v), ss = wredsum(v*v);
  int wid=t>>6, lane=t&63;
  if(lane==0){ red[wid]=s; red[4+wid]=ss; }
  __syncthreads();
  float S  = red[0]+red[1]+red[2]+red[3];
  float SS = red[4]+red[5]+red[6]+red[7];
  float m = S*(1.0f/256.0f);
  float r = rsqrtf(SS*(1.0f/256.0f) - m*m + 1e-5f);
  sn[t] = (v-m)*r*g[t]+bbv[t];
  __syncthreads();
  const uint4* w4 = (const uint4*)(M2h + (size_t)t*256);
  float acc=0.f;
#pragma unroll 4
  for(int kk=0;kk<32;kk++){
    U4 w; w.u=w4[kk];
#pragma unroll
    for(int q=0;q<4;q++){
      float2 f=__half22float2(w.h[q]);
      acc += sn[kk*8+2*q]*f.x + sn[kk*8+2*q+1]*f.y;
    }
  }
  qs[row*256+t]=acc;
}

// ---------------- fused attention: dots+softmax -> w -> partial agg (atomic) ----------------
__global__ __launch_bounds__(256) void k_att(const __half* __restrict__ x, const float* __restrict__ qs,
                                             float* __restrict__ aggF, float* __restrict__ wsumF){
  int b = blockIdx.x>>4;
  int t = threadIdx.x;
  size_t j = (size_t)blockIdx.x*256 + t;
  __shared__ __align__(16) float qt[256][8];
  __shared__ __align__(16) float wl[256][8];
  __shared__ __align__(16) float aggl[4][2048];
  __shared__ float wsl[4][8];
  const float* qb = qs + b*2048;
  for(int e=t;e<2048;e+=256) qt[e&255][e>>8]=qb[e];
  __syncthreads();
  const uint4* xr = (const uint4*)(x + j*DD);
  float pd[8]={0,0,0,0,0,0,0,0};
#pragma unroll 2
  for(int ch=0; ch<32; ch++){
    uint4 u = xr[ch];
    float2 f0=u2f2(u.x), f1=u2f2(u.y), f2=u2f2(u.z), f3=u2f2(u.w);
    float xv[8]={f0.x,f0.y,f1.x,f1.y,f2.x,f2.y,f3.x,f3.y};
    int c0=ch*8;
#pragma unroll
    for(int cc=0;cc<8;cc++){
      const float4* qp=(const float4*)&qt[c0+cc][0];
      float4 qa=qp[0], qc=qp[1];
      float xvv=xv[cc];
      pd[0]+=qa.x*xvv; pd[1]+=qa.y*xvv; pd[2]+=qa.z*xvv; pd[3]+=qa.w*xvv;
      pd[4]+=qc.x*xvv; pd[5]+=qc.y*xvv; pd[6]+=qc.z*xvv; pd[7]+=qc.w*xvv;
    }
  }
  float mx=pd[0];
#pragma unroll
  for(int i=1;i<8;i++) mx=fmaxf(mx,pd[i]);
  float ev[8]; float ssum=0.f;
#pragma unroll
  for(int i=0;i<8;i++){ ev[i]=__expf(pd[i]-mx); ssum+=ev[i]; }
  float inv=1.0f/ssum;
#pragma unroll
  for(int i=0;i<8;i++) wl[t][i]=ev[i]*inv+1e-5f;
  __syncthreads();
  int wid=t>>6, lane=t&63;
  float acc[8][4];
#pragma unroll
  for(int i=0;i<8;i++){ acc[i][0]=0;acc[i][1]=0;acc[i][2]=0;acc[i][3]=0; }
  float ws[8]={0,0,0,0,0,0,0,0};
  for(int r=0;r<64;r++){
    int jl = wid*64 + r;
    uint2 u = ((const uint2*)(x + ((size_t)blockIdx.x*256 + jl)*DD))[lane];
    float2 f01=u2f2(u.x), f23=u2f2(u.y);
    const float4* wp=(const float4*)&wl[jl][0];
    float4 wa=wp[0], wb_=wp[1];
    float wv[8]={wa.x,wa.y,wa.z,wa.w,wb_.x,wb_.y,wb_.z,wb_.w};
    float xv[4]={f01.x,f01.y,f23.x,f23.y};
#pragma unroll
    for(int i=0;i<8;i++){
      acc[i][0]+=wv[i]*xv[0]; acc[i][1]+=wv[i]*xv[1];
      acc[i][2]+=wv[i]*xv[2]; acc[i][3]+=wv[i]*xv[3];
      ws[i]+=wv[i];
    }
  }
#pragma unroll
  for(int i=0;i<8;i++){
    float4 st={acc[i][0],acc[i][1],acc[i][2],acc[i][3]};
    *((float4*)&aggl[wid][i*256 + lane*4])=st;
  }
  if(lane==0){
#pragma unroll
    for(int i=0;i<8;i++) wsl[wid][i]=ws[i];
  }
  __syncthreads();
  float* ab = aggF + (size_t)b*2048;
  for(int e=t;e<2048;e+=256)
    atomicAdd(&ab[e], aggl[0][e]+aggl[1][e]+aggl[2][e]+aggl[3][e]);
  if(t<8) atomicAdd(&wsumF[b*8+t], wsl[0][t]+wsl[1][t]+wsl[2][t]+wsl[3][t]);
}

// ---------------- t_gates: gl[512][1536] = [(agg*fac)@WC^T+bih | slotsh@Whh^T+bhh] ----------------
__global__ __launch_bounds__(256) void t_gates(const float* __restrict__ aggF,
    const float* __restrict__ wsumF,
    const __half* __restrict__ slotsh, const __half* __restrict__ Wg,
    const float* __restrict__ bih, const float* __restrict__ bhh,
    float* __restrict__ gl){
  int rt=blockIdx.x&15, ct=blockIdx.x>>4;
  int t=threadIdx.x;
  int r0=rt*32, c0=ct*64;
  __shared__ __align__(16) float Af[32][264];
  __shared__ __align__(16) float Wf[64][68];
  __shared__ float facS[32];
  if(ct<12){
    if(t<32) facS[t]=4096.0f/wsumF[r0+t];
    __syncthreads();
#pragma unroll
    for(int q=0;q<8;q++){
      int u=q*256+t;
      int row=u>>6, c4=u&63;
      float4 v=((const float4*)(aggF+(size_t)(r0+row)*256))[c4];
      float f=facS[row];
      v.x*=f; v.y*=f; v.z*=f; v.w*=f;
      *(float4*)&Af[row][c4*4]=v;
    }
  } else {
#pragma unroll
    for(int q=0;q<4;q++){
      int u=q*256+t;
      int row=u>>5, kk=u&31;
      st8(&Af[row][kk*8], ((const uint4*)(slotsh + ((size_t)(r0+row))*256))[kk]);
    }
  }
  float acc[2][4]={{0,0,0,0},{0,0,0,0}};
  int tx=t&15, ty=t>>4;
  for(int kc=0;kc<4;kc++){
    __syncthreads();
#pragma unroll
    for(int q=0;q<2;q++){
      int u=q*256+t;
      int kk=u>>3, cb=u&7;
      st8(&Wf[kk][cb*8], ((const uint4*)(Wg + (size_t)(kc*64+kk)*1536 + c0))[cb]);
    }
    __syncthreads();
#pragma unroll
    for(int k4=0;k4<16;k4++){
      float4 a0=*(const float4*)&Af[ty][kc*64+k4*4];
      float4 a1=*(const float4*)&Af[ty+16][kc*64+k4*4];
      float av0[4]={a0.x,a0.y,a0.z,a0.w};
      float av1[4]={a1.x,a1.y,a1.z,a1.w};
#pragma unroll
      for(int jj=0;jj<4;jj++){
        float4 wv=*(const float4*)&Wf[k4*4+jj][tx*4];
        acc[0][0]+=av0[jj]*wv.x; acc[0][1]+=av0[jj]*wv.y; acc[0][2]+=av0[jj]*wv.z; acc[0][3]+=av0[jj]*wv.w;
        acc[1][0]+=av1[jj]*wv.x; acc[1][1]+=av1[jj]*wv.y; acc[1][2]+=av1[jj]*wv.z; acc[1][3]+=av1[jj]*wv.w;
      }
    }
  }
  int col=c0+tx*4;
  const float* bb=(ct<12)? bih : bhh;
  int bcol=(ct<12)? col : col-768;
  float4 bv=*(const float4*)&bb[bcol];
  float4 o0={acc[0][0]+bv.x, acc[0][1]+bv.y, acc[0][2]+bv.z, acc[0][3]+bv.w};
  float4 o1={acc[1][0]+bv.x, acc[1][1]+bv.y, acc[1][2]+bv.z, acc[1][3]+bv.w};
  *(float4*)&gl[(size_t)(r0+ty)*1536+col]=o0;
  *(float4*)&gl[(size_t)(r0+ty+16)*1536+col]=o1;
}

// ---------------- t_gruln: GRU nonlinearity + MLP pre-norm ----------------
__global__ __launch_bounds__(512) void t_gruln(const float* __restrict__ gl, const float* __restrict__ slots,
    const float* __restrict__ lm_g, const float* __restrict__ lm_b,
    float* __restrict__ hb, __half* __restrict__ ysh){
  int t=threadIdx.x;
  int r=t>>8, c=t&255; int row=blockIdx.x*2+r;
  __shared__ float redS[2][4], redQ[2][4];
  const float* gr = gl + (size_t)row*1536;
  float gir=gr[c], giz=gr[256+c], gin=gr[512+c];
  float ghr=gr[768+c], ghz=gr[1024+c], ghn=gr[1280+c];
  float hp = slots[(size_t)row*256+c];
  float rr=sigm(gir+ghr), z=sigm(giz+ghz);
  float n=tanhf(gin+rr*ghn);
  float hv=(1.0f-z)*n+z*hp;
  hb[(size_t)row*256+c]=hv;
  float s=wredsum(hv), ss=wredsum(hv*hv);
  if((t&63)==0){ redS[r][(t>>6)&3]=s; redQ[r][(t>>6)&3]=ss; }
  __syncthreads();
  float S=redS[r][0]+redS[r][1]+redS[r][2]+redS[r][3];
  float SS=redQ[r][0]+redQ[r][1]+redQ[r][2]+redQ[r][3];
  float m=S*(1.0f/256.0f);
  float rs=rsqrtf(SS*(1.0f/256.0f)-m*m+1e-5f);
  ysh[(size_t)row*256+c]=__float2half((hv-m)*rs*lm_g[c]+lm_b[c]);
}

// ---------------- t_mlp1: z1h[512][1024] = lrelu(ysh@W1^T + b1) ----------------
__global__ __launch_bounds__(256) void t_mlp1(const __half* __restrict__ ysh,
    const __half* __restrict__ W1t, const float* __restrict__ b1,
    __half* __restrict__ z1h){
  int rt=blockIdx.x&15, ct=blockIdx.x>>4;
  int t=threadIdx.x;
  int r0=rt*32, c0=ct*64;
  __shared__ __align__(16) float Af[32][264];
  __shared__ __align__(16) float Wf[64][68];
#pragma unroll
  for(int q=0;q<4;q++){
    int u=q*256+t; int row=u>>5, kk=u&31;
    st8(&Af[row][kk*8], ((const uint4*)(ysh + ((size_t)(r0+row))*256))[kk]);
  }
  float acc[2][4]={{0,0,0,0},{0,0,0,0}};
  int tx=t&15, ty=t>>4;
  for(int kc=0;kc<4;kc++){
    __syncthreads();
#pragma unroll
    for(int q=0;q<2;q++){
      int u=q*256+t; int kk=u>>3, cb=u&7;
      st8(&Wf[kk][cb*8], ((const uint4*)(W1t + (size_t)(kc*64+kk)*1024 + c0))[cb]);
    }
    __syncthreads();
#pragma unroll
    for(int k4=0;k4<16;k4++){
      float4 a0=*(const float4*)&Af[ty][kc*64+k4*4];
      float4 a1=*(const float4*)&Af[ty+16][kc*64+k4*4];
      float av0[4]={a0.x,a0.y,a0.z,a0.w};
      float av1[4]={a1.x,a1.y,a1.z,a1.w};
#pragma unroll
      for(int jj=0;jj<4;jj++){
        float4 wv=*(const float4*)&Wf[k4*4+jj][tx*4];
        acc[0][0]+=av0[jj]*wv.x; acc[0][1]+=av0[jj]*wv.y; acc[0][2]+=av0[jj]*wv.z; acc[0][3]+=av0[jj]*wv.w;
        acc[1][0]+=av1[jj]*wv.x; acc[1][1]+=av1[jj]*wv.y; acc[1][2]+=av1[jj]*wv.z; acc[1][3]+=av1[jj]*wv.w;
      }
    }
  }
  int col=c0+tx*4;
  float4 bv=*(const float4*)&b1[col];
#pragma unroll
  for(int rr2=0;rr2<2;rr2++){
    float v0=acc[rr2][0]+bv.x, v1=acc[rr2][1]+bv.y, v2=acc[rr2][2]+bv.z, v3=acc[rr2][3]+bv.w;
    v0=v0>0.f?v0:0.01f*v0; v1=v1>0.f?v1:0.01f*v1;
    v2=v2>0.f?v2:0.01f*v2; v3=v3>0.f?v3:0.01f*v3;
    __half2 p0=__floats2half2_rn(v0,v1), p1=__floats2half2_rn(v2,v3);
    uint2 u2; __builtin_memcpy(&u2.x,&p0,4); __builtin_memcpy(&u2.y,&p1,4);
    *(uint2*)&z1h[(size_t)(r0+ty+rr2*16)*1024+col]=u2;
  }
}

// ---------------- t_mlp2p: partial z1h@W2^T, K=1024 split 8x128 ----------------
__global__ __launch_bounds__(256) void t_mlp2p(const __half* __restrict__ z1h,
    const __half* __restrict__ W2t, float* __restrict__ pp){
  int b=blockIdx.x;
  int rt=b&15, ct=(b>>4)&3, kc=b>>6;
  int t=threadIdx.x;
  int r0=rt*32, c0=ct*64;
  __shared__ __align__(16) float Af[32][136];
  __shared__ __align__(16) float Wf[128][68];
#pragma unroll
  for(int q=0;q<2;q++){
    int u=q*256+t;
    int row=u>>4, seg=u&15;
    st8(&Af[row][seg*8], ((const uint4*)(z1h + (size_t)(r0+row)*1024 + kc*128))[seg]);
  }
#pragma unroll
  for(int q=0;q<4;q++){
    int u=q*256+t;
    int kk=u>>3, cb=u&7;
    st8(&Wf[kk][cb*8], ((const uint4*)(W2t + (size_t)(kc*128+kk)*256 + c0))[cb]);
  }
  __syncthreads();
  float acc[2][4]={{0,0,0,0},{0,0,0,0}};
  int tx=t&15, ty=t>>4;
#pragma unroll
  for(int k4=0;k4<32;k4++){
    float4 a0=*(const float4*)&Af[ty][k4*4];
    float4 a1=*(const float4*)&Af[ty+16][k4*4];
    float av0[4]={a0.x,a0.y,a0.z,a0.w};
    float av1[4]={a1.x,a1.y,a1.z,a1.w};
#pragma unroll
    for(int jj=0;jj<4;jj++){
      float4 wv=*(const float4*)&Wf[k4*4+jj][tx*4];
      acc[0][0]+=av0[jj]*wv.x; acc[0][1]+=av0[jj]*wv.y; acc[0][2]+=av0[jj]*wv.z; acc[0][3]+=av0[jj]*wv.w;
      acc[1][0]+=av1[jj]*wv.x; acc[1][1]+=av1[jj]*wv.y; acc[1][2]+=av1[jj]*wv.z; acc[1][3]+=av1[jj]*wv.w;
    }
  }
  int col=c0+tx*4;
  float4 o0={acc[0][0],acc[0][1],acc[0][2],acc[0][3]};
  float4 o1={acc[1][0],acc[1][1],acc[1][2],acc[1][3]};
  *(float4*)&pp[((size_t)kc*512 + r0+ty)*256+col]=o0;
  *(float4*)&pp[((size_t)kc*512 + r0+ty+16)*256+col]=o1;
}

// ---------------- t_fin: reduce partials + residual; slot-LN + qs (non-last) ----------------
__global__ __launch_bounds__(512) void t_fin(const float* __restrict__ hb, const float* __restrict__ pp,
    const float* __restrict__ b2, const float* __restrict__ ls_g, const float* __restrict__ ls_b,
    const __half* __restrict__ M2h, float* __restrict__ dst,
    __half* __restrict__ slotsh, float* __restrict__ qs, int last){
  int t=threadIdx.x;
  int r=t>>8, c=t&255; int row=blockIdx.x*2+r;
  __shared__ float ysl[2][256];
  __shared__ float redS[2][4], redQ[2][4];
  float s = hb[(size_t)row*256+c] + b2[c];
#pragma unroll
  for(int kc=0;kc<8;kc++) s += pp[((size_t)kc*512+row)*256+c];
  dst[(size_t)row*256+c]=s;
  if(last) return;
  slotsh[(size_t)row*256+c]=__float2half(s);
  float su=wredsum(s), sq=wredsum(s*s);
  if((t&63)==0){ redS[r][(t>>6)&3]=su; redQ[r][(t>>6)&3]=sq; }
  __syncthreads();
  float S=redS[r][0]+redS[r][1]+redS[r][2]+redS[r][3];
  float SS=redQ[r][0]+redQ[r][1]+redQ[r][2]+redQ[r][3];
  float m=S*(1.0f/256.0f);
  float rs=rsqrtf(SS*(1.0f/256.0f)-m*m+1e-5f);
  ysl[r][c]=(s-m)*rs*ls_g[c]+ls_b[c];
  __syncthreads();
  const uint4* m4=(const uint4*)(M2h+(size_t)c*256);
  float acc=0.f;
#pragma unroll 4
  for(int kk=0;kk<32;kk++){
    U4 w; w.u=m4[kk];
#pragma unroll
    for(int q=0;q<4;q++){
      float2 f=__half22float2(w.h[q]);
      acc += ysl[r][kk*8+2*q]*f.x + ysl[r][kk*8+2*q+1]*f.y;
    }
  }
  qs[(size_t)row*256+c]=acc;
}

extern "C" void kernel_launch(void* const* d_in, const int* in_sizes, int n_in,
                              void* d_out, int out_size, void* d_ws, size_t ws_size,
                              hipStream_t stream){
  const float* inputs=(const float*)d_in[0];
  const float* sinit =(const float*)d_in[1];
  const float* Wq =(const float*)d_in[2];
  const float* Wk =(const float*)d_in[3];
  const float* Wv =(const float*)d_in[4];
  const float* Wih=(const float*)d_in[5];
  const float* Whh=(const float*)d_in[6];
  const float* bih=(const float*)d_in[7];
  const float* bhh=(const float*)d_in[8];
  const float* lin_g=(const float*)d_in[9];
  const float* lin_b=(const float*)d_in[10];
  const float* ls_g=(const float*)d_in[11];
  const float* ls_b=(const float*)d_in[12];
  const float* lm_g=(const float*)d_in[13];
  const float* lm_b=(const float*)d_in[14];
  const float* W1=(const float*)d_in[15];
  const float* b1=(const float*)d_in[16];
  const float* W2=(const float*)d_in[17];
  const float* b2=(const float*)d_in[18];

  char* w=(char*)d_ws;
  __half* x    =(__half*)w; w += (size_t)BB*NN*DD*2;        // 134.2 MB
  float* qs    =(float*)w;  w += 512*256*4;
  float* slots =(float*)w;  w += 512*256*4;
  __half* slotsh=(__half*)w; w += 512*256*2;
  __half* M2h  =(__half*)w; w += 256*256*2;
  __half* Wg   =(__half*)w; w += 256*1536*2;
  __half* W1t  =(__half*)w; w += 256*1024*2;
  __half* W2t  =(__half*)w; w += 1024*256*2;
  float* hb    =(float*)w;  w += 512*256*4;
  __half* ysh  =(__half*)w; w += 512*256*2;
  __half* z1h  =(__half*)w; w += (size_t)512*1024*2;
  float* pp    =(float*)w;  w += (size_t)8*512*256*4;       // 4.2 MB
  float* gl_   =(float*)w;  w += (size_t)512*1536*4;        // 3.1 MB
  float* aggZ  =(float*)w;  w += (size_t)(3*512*256 + 3*512)*4;

  float* aggF[3]; float* wsumF[3];
  for(int i=0;i<3;i++){ aggF[i]=aggZ + (size_t)i*512*256; wsumF[i]=aggZ + (size_t)3*512*256 + (size_t)i*512; }

  hipLaunchKernelGGL(kp_all, dim3(4230), dim3(256), 0, stream,
                     Whh, W1, W2, sinit, Wih, Wv, Wq, Wk,
                     Wg, W1t, W2t, slots, M2h, aggZ);
  hipLaunchKernelGGL(k_ln_x, dim3(65536),dim3(256), 0, stream, inputs, lin_g, lin_b, x);
  hipLaunchKernelGGL(k_pre,  dim3(512),  dim3(256), 0, stream, slots, ls_g, ls_b, M2h, qs, slotsh);
  for(int it=0; it<NITER; ++it){
    int last = (it==NITER-1);
    float* dst = last ? (float*)d_out : slots;
    hipLaunchKernelGGL(k_att,   dim3(1024), dim3(256), 0, stream, x, qs, aggF[it], wsumF[it]);
    hipLaunchKernelGGL(t_gates, dim3(384),  dim3(256), 0, stream, aggF[it], wsumF[it], slotsh, Wg, bih, bhh, gl_);
    hipLaunchKernelGGL(t_gruln, dim3(256),  dim3(512), 0, stream, gl_, slots, lm_g, lm_b, hb, ysh);
    hipLaunchKernelGGL(t_mlp1,  dim3(256),  dim3(256), 0, stream, ysh, W1t, b1, z1h);
    hipLaunchKernelGGL(t_mlp2p, dim3(512),  dim3(256), 0, stream, z1h, W2t, pp);
    hipLaunchKernelGGL(t_fin,   dim3(256),  dim3(512), 0, stream, hb, pp, b2, ls_g, ls_b, M2h,
                       dst, slotsh, qs, last);
  }
}